// Round 3
// baseline (445.255 us; speedup 1.0000x reference)
//
#include <hip/hip_runtime.h>

#define Bv 32
#define Tv 2048
#define Hv 512
#define Dv 1024

using bf16x8 = __attribute__((ext_vector_type(8))) __bf16;
using bf16x4 = __attribute__((ext_vector_type(4))) __bf16;
using f32x4  = __attribute__((ext_vector_type(4))) float;

// ---------------------------------------------------------------------------
// Prep kernel (fused): blocks 0..255 swizzle We -> bf16 B-fragment order;
// blocks 256..767 compute hp[b][h] = hidden[b,:].Wh[h,:] + b_attn[h].
// ---------------------------------------------------------------------------
__global__ void prep_kernel(const float* __restrict__ W, bf16x8* __restrict__ We_sw,
                            const float* __restrict__ hidden,
                            const float* __restrict__ b_attn, float* __restrict__ hp) {
    if (blockIdx.x < 256) {
        int g = blockIdx.x * 256 + threadIdx.x;   // 0..65535
        int h = g >> 7;                           // 512 rows
        int d = (g & 127) * 8;                    // 8 consecutive d's
        const float* src = W + h * (2 * Dv) + Dv + d;
        float4 f0 = *(const float4*)src;
        float4 f1 = *(const float4*)(src + 4);
        bf16x8 o;
        o[0] = (__bf16)f0.x; o[1] = (__bf16)f0.y; o[2] = (__bf16)f0.z; o[3] = (__bf16)f0.w;
        o[4] = (__bf16)f1.x; o[5] = (__bf16)f1.y; o[6] = (__bf16)f1.z; o[7] = (__bf16)f1.w;
        int s = ((h >> 4) * 32 + (d >> 5)) * 64 + (((d >> 3) & 3) << 4) + (h & 15);
        We_sw[s] = o;
    } else {
        int h   = blockIdx.x - 256;
        int tid = threadIdx.x;           // 256
        float4 wh = ((const float4*)(W + h * (2 * Dv)))[tid];
        __shared__ float red[4][Bv];
        int lane = tid & 63, w = tid >> 6;
        for (int b = 0; b < Bv; ++b) {
            float4 x = ((const float4*)(hidden + b * Dv))[tid];
            float p = wh.x * x.x + wh.y * x.y + wh.z * x.z + wh.w * x.w;
#pragma unroll
            for (int m = 1; m < 64; m <<= 1) p += __shfl_xor(p, m);
            if (lane == 0) red[w][b] = p;
        }
        __syncthreads();
        if (tid < Bv)
            hp[tid * Hv + h] = red[0][tid] + red[1][tid] + red[2][tid] + red[3][tid] + b_attn[h];
    }
}

__device__ __forceinline__ float fast_tanh(float x) {
    float xc = fminf(fmaxf(x, -9.0f), 9.0f);
    float e  = __expf(2.0f * xc);
    return 1.0f - 2.0f / (e + 1.0f);
}

// ---------------------------------------------------------------------------
// Main kernel: scores[b,t] = sum_h v[h]*tanh( enc[b,t,:].We[h,:] + hp[b,h] )
// Block = 64 rows x 512 h, 8 waves. Fragment-order LDS A-tile (linear, zero
// conflicts both sides), double-buffered, ONE lgkm-only barrier per chunk
// (vmcnt NOT drained -> global prefetch stays in flight across barriers),
// A global loads depth-2 pipelined, B fragments register-prefetched depth-1.
// ---------------------------------------------------------------------------
__global__ __launch_bounds__(512, 2) void attn_main(
    const float* __restrict__ enc, const bf16x8* __restrict__ Bg,
    const float* __restrict__ hp, const float* __restrict__ vvec,
    float* __restrict__ scores)
{
    __shared__ bf16x8 Abuf[2][512];      // 2 x 8 KB, fragment order
    __shared__ float redbuf[8][64];

    const int tid   = threadIdx.x;
    const int lane  = tid & 63;
    const int w     = tid >> 6;          // wave 0..7
    const int row0  = blockIdx.x * 64;
    const int batch = row0 >> 11;

    // --- A staging map: coalesced global (wave = 4 rows x 256B contiguous),
    // transpose happens in the LDS write address.
    const int srow = tid >> 4;           // 0..31 (second load: +32)
    const int kk   = (tid & 15) * 4;     // 0..60 within 64-col chunk
    const float* gA = enc + (row0 + srow) * Dv + kk;
    const int mt0  = srow >> 4, aa = srow & 15;
    const int ktl0 = kk >> 5,  qq = (kk >> 3) & 3, jb = kk & 7;
    // fragment slot = (mt*2+ktl)*64 + aa*4 + qq ; elem offset jb
    __bf16* lw = (__bf16*)(&Abuf[0][0]) + (((mt0 * 2 + ktl0) * 64 + aa * 4 + qq) << 3) + jb;
    // second row-half (mt+2): +256 slots = +2048 elems; buffer 1: +512 slots = +4096 elems

    // --- B fragment base: frag(j,ktl,kc) at Bg[((w*4+j)*32 + kc*2+ktl)*64 + lane]
    const bf16x8* Bptr = Bg + (w * 128) * 64 + lane;

    f32x4 acc[4][4];
#pragma unroll
    for (int i = 0; i < 4; ++i)
#pragma unroll
        for (int j = 0; j < 4; ++j)
            acc[i][j] = (f32x4){0.f, 0.f, 0.f, 0.f};

    // prologue: A chunks 0,1 in flight; B chunk 0 in flight
    float4 fa0 = *(const float4*)gA;
    float4 fa1 = *(const float4*)(gA + 32 * Dv);
    float4 fb0 = *(const float4*)(gA + 64);
    float4 fb1 = *(const float4*)(gA + 32 * Dv + 64);
    bf16x8 Bc[2][4];
#pragma unroll
    for (int ktl = 0; ktl < 2; ++ktl)
#pragma unroll
        for (int j = 0; j < 4; ++j)
            Bc[ktl][j] = Bptr[(j * 32 + ktl) * 64];

    const int rsl = ((lane & 15) << 2) + (lane >> 4);   // read slot within fragment group

#pragma unroll
    for (int kc = 0; kc < 16; ++kc) {
        // convert + store A(kc) into buf kc&1 (waits only on fa0/fa1, issued 2 chunks ago)
        __bf16* p = lw + (kc & 1) * 4096;
        bf16x4 o0, o1;
        o0[0] = (__bf16)fa0.x; o0[1] = (__bf16)fa0.y; o0[2] = (__bf16)fa0.z; o0[3] = (__bf16)fa0.w;
        o1[0] = (__bf16)fa1.x; o1[1] = (__bf16)fa1.y; o1[2] = (__bf16)fa1.z; o1[3] = (__bf16)fa1.w;
        *(bf16x4*)p          = o0;
        *(bf16x4*)(p + 2048) = o1;

        // LDS-visibility-only barrier: does NOT drain vmcnt -> prefetches live on
        asm volatile("s_waitcnt lgkmcnt(0)\n\ts_barrier" ::: "memory");

        // rotate A pipeline; issue A(kc+2)
        fa0 = fb0; fa1 = fb1;
        if (kc < 14) {
            fb0 = *(const float4*)(gA + (kc + 2) * 64);
            fb1 = *(const float4*)(gA + 32 * Dv + (kc + 2) * 64);
        }
        // issue B(kc+1) prefetch (L2-resident, hidden under this chunk's MFMAs)
        bf16x8 Bn[2][4];
        if (kc < 15) {
#pragma unroll
            for (int ktl = 0; ktl < 2; ++ktl)
#pragma unroll
                for (int j = 0; j < 4; ++j)
                    Bn[ktl][j] = Bptr[(j * 32 + (kc + 1) * 2 + ktl) * 64];
        }

        const bf16x8* rb = &Abuf[kc & 1][0];
#pragma unroll
        for (int ktl = 0; ktl < 2; ++ktl) {
            bf16x8 a0 = rb[(0 * 2 + ktl) * 64 + rsl];
            bf16x8 a1 = rb[(1 * 2 + ktl) * 64 + rsl];
            bf16x8 a2 = rb[(2 * 2 + ktl) * 64 + rsl];
            bf16x8 a3 = rb[(3 * 2 + ktl) * 64 + rsl];
#pragma unroll
            for (int j = 0; j < 4; ++j) {
                acc[0][j] = __builtin_amdgcn_mfma_f32_16x16x32_bf16(a0, Bc[ktl][j], acc[0][j], 0, 0, 0);
                acc[1][j] = __builtin_amdgcn_mfma_f32_16x16x32_bf16(a1, Bc[ktl][j], acc[1][j], 0, 0, 0);
                acc[2][j] = __builtin_amdgcn_mfma_f32_16x16x32_bf16(a2, Bc[ktl][j], acc[2][j], 0, 0, 0);
                acc[3][j] = __builtin_amdgcn_mfma_f32_16x16x32_bf16(a3, Bc[ktl][j], acc[3][j], 0, 0, 0);
            }
        }
#pragma unroll
        for (int ktl = 0; ktl < 2; ++ktl)
#pragma unroll
            for (int j = 0; j < 4; ++j)
                Bc[ktl][j] = Bn[ktl][j];
    }

    // Epilogue. C/D layout: col = lane&15, row = (lane>>4)*4 + reg
    float hpv[4], vv[4];
#pragma unroll
    for (int j = 0; j < 4; ++j) {
        int n  = w * 64 + j * 16 + (lane & 15);
        hpv[j] = hp[batch * Hv + n];
        vv[j]  = vvec[n];
    }
    const int qrow = (lane >> 4) * 4;
#pragma unroll
    for (int mt = 0; mt < 4; ++mt)
#pragma unroll
        for (int r = 0; r < 4; ++r) {
            float p = 0.f;
#pragma unroll
            for (int j = 0; j < 4; ++j)
                p += vv[j] * fast_tanh(acc[mt][j][r] + hpv[j]);
            p += __shfl_xor(p, 1);
            p += __shfl_xor(p, 2);
            p += __shfl_xor(p, 4);
            p += __shfl_xor(p, 8);
            if ((lane & 15) == 0)
                redbuf[w][mt * 16 + qrow + r] = p;
        }
    __syncthreads();
    if (tid < 64) {
        float s = 0.f;
#pragma unroll
        for (int ww = 0; ww < 8; ++ww) s += redbuf[ww][tid];
        scores[row0 + tid] = s;
    }
}

// ---------------------------------------------------------------------------
// Softmax over T per batch row (fp32)
// ---------------------------------------------------------------------------
__global__ void softmax_kernel(const float* __restrict__ scores, float* __restrict__ out) {
    int b   = blockIdx.x;
    int tid = threadIdx.x;               // 256
    const float* s = scores + b * Tv;
    float local[8];
    float m = -1e30f;
#pragma unroll
    for (int i = 0; i < 8; ++i) { local[i] = s[tid + i * 256]; m = fmaxf(m, local[i]); }
    __shared__ float red[4];
    int lane = tid & 63, w = tid >> 6;
#pragma unroll
    for (int x = 1; x < 64; x <<= 1) m = fmaxf(m, __shfl_xor(m, x));
    if (lane == 0) red[w] = m;
    __syncthreads();
    m = fmaxf(fmaxf(red[0], red[1]), fmaxf(red[2], red[3]));
    float sum = 0.f;
#pragma unroll
    for (int i = 0; i < 8; ++i) { local[i] = expf(local[i] - m); sum += local[i]; }
#pragma unroll
    for (int x = 1; x < 64; x <<= 1) sum += __shfl_xor(sum, x);
    __syncthreads();
    if (lane == 0) red[w] = sum;
    __syncthreads();
    sum = red[0] + red[1] + red[2] + red[3];
    float inv = 1.0f / sum;
#pragma unroll
    for (int i = 0; i < 8; ++i) out[b * Tv + tid + i * 256] = local[i] * inv;
}

// ---------------------------------------------------------------------------
extern "C" void kernel_launch(void* const* d_in, const int* in_sizes, int n_in,
                              void* d_out, int out_size, void* d_ws, size_t ws_size,
                              hipStream_t stream) {
    const float* hidden = (const float*)d_in[0];   // (32, 1024)
    const float* enc    = (const float*)d_in[1];   // (32, 2048, 1024)
    const float* W      = (const float*)d_in[2];   // (512, 2048)
    const float* b_attn = (const float*)d_in[3];   // (512,)
    const float* v      = (const float*)d_in[4];   // (512,)
    float* out = (float*)d_out;                    // (32, 1, 2048) fp32

    char* ws = (char*)d_ws;
    bf16x8* We_sw = (bf16x8*)ws;                          // 1 MB
    float*  hp    = (float*)(ws + (1 << 20));             // 64 KB
    float*  sc    = (float*)(ws + (1 << 20) + (1 << 16)); // 256 KB

    prep_kernel<<<768, 256, 0, stream>>>(W, We_sw, hidden, b_attn, hp);
    attn_main<<<(Bv * Tv) / 64, 512, 0, stream>>>(enc, We_sw, hp, v, sc);
    softmax_kernel<<<Bv, 256, 0, stream>>>(sc, out);
}